// Round 5
// baseline (330.734 us; speedup 1.0000x reference)
//
#include <hip/hip_runtime.h>
#include <math.h>

#define N_NODES 20000
#define N_EDGES 160000
#define NODE_DIM 64
#define EDGE_DIM 16
#define H 32
#define STEPS 3

// ---------------------------------------------------------------------------
// CSR-by-src build (once per call): hist -> 2-level scan -> atomic fill that
// emits src-sorted dst2/eperm; ef permuted into ef2 (coalesced writes).
// ---------------------------------------------------------------------------
__global__ void hist_src_kernel(const int* __restrict__ ei, int* __restrict__ deg) {
    int e = blockIdx.x * 256 + threadIdx.x;
    if (e < N_EDGES) atomicAdd(&deg[ei[e]], 1);               // row 0 = src
}

__global__ void scan_a_kernel(const int* __restrict__ deg,
                              int* __restrict__ part, int* __restrict__ bsum) {
    __shared__ int s[256];
    int v = blockIdx.x * 256 + threadIdx.x;
    int x = (v < N_NODES) ? deg[v] : 0;
    s[threadIdx.x] = x;
    __syncthreads();
    for (int off = 1; off < 256; off <<= 1) {
        int t = (threadIdx.x >= off) ? s[threadIdx.x - off] : 0;
        __syncthreads();
        s[threadIdx.x] += t;
        __syncthreads();
    }
    if (v < N_NODES) part[v] = s[threadIdx.x] - x;
    if (threadIdx.x == 255) bsum[blockIdx.x] = s[255];
}

__global__ void scan_b_kernel(int* __restrict__ rowptr,
                              const int* __restrict__ bsum,
                              int* __restrict__ cursor) {
    __shared__ int boff[80];
    if (threadIdx.x == 0) {
        int run = 0;
        for (int b = 0; b < 79; ++b) { boff[b] = run; run += bsum[b]; }
    }
    __syncthreads();
    for (int v = threadIdx.x; v < N_NODES; v += 256) {
        int r = rowptr[v] + boff[v >> 8];
        rowptr[v] = r;
        cursor[v] = r;
    }
    if (threadIdx.x == 0) rowptr[N_NODES] = N_EDGES;
}

__global__ void fill_src_kernel(const int* __restrict__ ei, int* __restrict__ cursor,
                                int* __restrict__ eperm, int* __restrict__ dst2) {
    int e = blockIdx.x * 256 + threadIdx.x;
    if (e < N_EDGES) {
        int s = ei[e];
        int slot = atomicAdd(&cursor[s], 1);
        eperm[slot] = e;
        dst2[slot]  = ei[N_EDGES + e];
    }
}

__global__ void permute_ef_kernel(const float* __restrict__ ef,
                                  const int* __restrict__ eperm,
                                  float* __restrict__ ef2) {
    int t = blockIdx.x * 256 + threadIdx.x;
    if (t < N_EDGES * EDGE_DIM) {
        int j = t >> 4;
        int d = t & 15;
        ef2[t] = ef[eperm[j] * EDGE_DIM + d];
    }
}

// ---------------------------------------------------------------------------
// node projection: h = node_feat @ W_np.T + b_np
// ---------------------------------------------------------------------------
__global__ void node_proj_kernel(const float* __restrict__ nf,
                                 const float* __restrict__ W,
                                 const float* __restrict__ b,
                                 float* __restrict__ h) {
    int tid = blockIdx.x * blockDim.x + threadIdx.x;
    if (tid >= N_NODES * H) return;
    int v = tid >> 5;
    int i = tid & 31;
    const float* __restrict__ row = nf + v * NODE_DIM;
    const float* __restrict__ w   = W + i * NODE_DIM;
    float acc = b[i];
#pragma unroll
    for (int d = 0; d < NODE_DIM; ++d) acc = fmaf(row[d], w[d], acc);
    h[tid] = acc;
}

// ---------------------------------------------------------------------------
// FUSED U-precompute + edge message, LDS-pipe minimized.
// Phase 1: thread t owns column c=t (weights in 32 VGPRs). h rows are read
//   DIRECTLY FROM GLOBAL with wave-uniform addresses -> compiler emits
//   s_load broadcasts (SMEM pipe), zero LDS traffic. U[n][c] stored linearly
//   at Ul[n*576 + c] (cols 512..543 pad, bias i at 544+i); consecutive-t
//   writes are conflict-free.
// Phase 2: wave w owns src nodes ls = w, w+9. Per node: lane l loads its U
//   slice ONCE into regs (cols [8l,8l+8) = output i=l>>1, d-half l&1; 2x
//   ds_read_b128 + bias) then loops the node's contiguous edge range:
//   ef via two L1 float4 loads, 8 FMAs, pair-reduce via __shfl_xor(.,1)
//   (DPP), predicated atomicAdd from even lanes. LDS cost ~6 cyc/edge
//   (amortized) vs ~75 before. Edge bounds/dst2 indices are wave-uniform
//   (readfirstlane) -> scalar loads.
// ---------------------------------------------------------------------------
__global__ __launch_bounds__(576)
void fused_msg_kernel(const float* __restrict__ We,
                      const float* __restrict__ be,
                      const float* __restrict__ h,
                      const int* __restrict__ rowptr,
                      const int* __restrict__ dst2,
                      const float* __restrict__ ef2,
                      float* __restrict__ m) {
    __shared__ float Ul[16 * 576];    // 36.9 KB
    int t  = threadIdx.x;
    int v0 = blockIdx.x * 16;

    // ---- per-thread weight column (registers) ----
    float wreg[32];
    int p = -1;
    if (t < 512) {
        int L = t >> 4, d = t & 15;
#pragma unroll
        for (int k = 0; k < H; ++k) wreg[k] = We[(L * H + k) * EDGE_DIM + d];
        p = t;
    } else if (t < 544) {
        int i = t - 512;
#pragma unroll
        for (int k = 0; k < H; ++k) wreg[k] = be[i * H + k];
        p = 544 + i;
    }

    // ---- phase 1: U into LDS; h via wave-uniform scalar broadcasts ----
    if (p >= 0) {
        for (int n = 0; n < 16; n += 2) {
            const float* __restrict__ h0 = h + (size_t)(v0 + n) * H;
            const float* __restrict__ h1 = h0 + H;
            float a0 = 0.f, a1 = 0.f;
#pragma unroll
            for (int k = 0; k < H; ++k) {
                a0 = fmaf(wreg[k], h0[k], a0);
                a1 = fmaf(wreg[k], h1[k], a1);
            }
            Ul[n * 576 + p]       = a0;
            Ul[(n + 1) * 576 + p] = a1;
        }
    }
    __syncthreads();

    // ---- phase 2: per-src-node register-resident U, edge loop ----
    int l   = t & 63;
    int wid = __builtin_amdgcn_readfirstlane(t >> 6);   // 0..8, wave-uniform
    int i   = l >> 1;       // output component this lane contributes to
    int dh  = l & 1;        // d-half: 0 -> d 0..7, 1 -> d 8..15

    for (int ls = wid; ls < 16; ls += 9) {
        const float4* __restrict__ us = (const float4*)(Ul + ls * 576 + l * 8);
        float4 uA = us[0];
        float4 uB = us[1];
        float  bv = Ul[ls * 576 + 544 + i];

        int jb = rowptr[v0 + ls];
        int je = rowptr[v0 + ls + 1];
        for (int j = jb; j < je; ++j) {
            const float4* __restrict__ ep =
                (const float4*)(ef2 + (size_t)j * EDGE_DIM + dh * 8);
            float4 ea = ep[0];
            float4 eb = ep[1];
            float pp = 0.f;
            pp = fmaf(ea.x, uA.x, pp);
            pp = fmaf(ea.y, uA.y, pp);
            pp = fmaf(ea.z, uA.z, pp);
            pp = fmaf(ea.w, uA.w, pp);
            pp = fmaf(eb.x, uB.x, pp);
            pp = fmaf(eb.y, uB.y, pp);
            pp = fmaf(eb.z, uB.z, pp);
            pp = fmaf(eb.w, uB.w, pp);
            float qq = pp + __shfl_xor(pp, 1, 64);      // pair-reduce (DPP)
            if (dh == 0) {
                int dd = dst2[j];                       // wave-uniform -> s_load
                atomicAdd(&m[(size_t)dd * H + i], bv + qq);
            }
        }
    }
}

// ---------------------------------------------------------------------------
// GRU v4: register-weight column-GEMM with scalar-broadcast x reads.
//   Thread c = tid&127 owns output column (gate gt = c>>5, comp ci = c&31);
//   weights in 16 float4 VGPRs. m/h rows read via wave-uniform s_load
//   broadcasts (half = tid>>7 readfirstlane'd) -> no xs staging, no LDS
//   reads in the GEMM. Gate exchange via pad-5 gs (conflict-free). m is
//   re-zeroed in phase C for the next step's atomics.
// ---------------------------------------------------------------------------
__global__ __launch_bounds__(256, 4)
void gru_kernel(const float* __restrict__ Wih,
                const float* __restrict__ Whh,
                const float* __restrict__ bih,
                const float* __restrict__ bhh,
                float* __restrict__ m,
                const float* __restrict__ h,
                float* __restrict__ hout) {
    __shared__ float gs[16 * 32 * 5];    // 10 KB

    int c = threadIdx.x & 127;
    float4 wc[16];
    if (c < 96) {
        const float4* p = (const float4*)(Wih + c * H);
#pragma unroll
        for (int q = 0; q < 8; ++q) wc[q] = p[q];
    } else {
#pragma unroll
        for (int q = 0; q < 8; ++q) wc[q] = make_float4(0.f, 0.f, 0.f, 0.f);
    }
    int hrow = (c < 64) ? c : ((c >= 96) ? (c - 32) : -1);
    if (hrow >= 0) {
        const float4* p = (const float4*)(Whh + hrow * H);
#pragma unroll
        for (int q = 0; q < 8; ++q) wc[8 + q] = p[q];
    } else {
#pragma unroll
        for (int q = 0; q < 8; ++q) wc[8 + q] = make_float4(0.f, 0.f, 0.f, 0.f);
    }
    float bias;
    if (c < 64)      bias = bih[c] + bhh[c];      // r_sum / z_sum
    else if (c < 96) bias = bih[c];               // in
    else             bias = bhh[c - 32];          // hn

    int half = __builtin_amdgcn_readfirstlane(threadIdx.x >> 7);  // 0 or 1
    int ci   = c & 31;
    int gt   = c >> 5;
    int v0   = blockIdx.x * 16;

    // ---- phase B: column-GEMM, scalar-broadcast x, 2-node ILP ----
#pragma unroll
    for (int n = 0; n < 8; n += 2) {
        int v = v0 + half * 8 + n;
        const float* __restrict__ m0 = m + (size_t)v * H;
        const float* __restrict__ m1 = m0 + H;
        const float* __restrict__ h0 = h + (size_t)v * H;
        const float* __restrict__ h1 = h0 + H;
        float acc0 = bias, acc1 = bias;
#pragma unroll
        for (int q = 0; q < 8; ++q) {
            float4 w = wc[q];
            acc0 = fmaf(w.x, m0[q * 4 + 0], acc0); acc1 = fmaf(w.x, m1[q * 4 + 0], acc1);
            acc0 = fmaf(w.y, m0[q * 4 + 1], acc0); acc1 = fmaf(w.y, m1[q * 4 + 1], acc1);
            acc0 = fmaf(w.z, m0[q * 4 + 2], acc0); acc1 = fmaf(w.z, m1[q * 4 + 2], acc1);
            acc0 = fmaf(w.w, m0[q * 4 + 3], acc0); acc1 = fmaf(w.w, m1[q * 4 + 3], acc1);
        }
#pragma unroll
        for (int q = 0; q < 8; ++q) {
            float4 w = wc[8 + q];
            acc0 = fmaf(w.x, h0[q * 4 + 0], acc0); acc1 = fmaf(w.x, h1[q * 4 + 0], acc1);
            acc0 = fmaf(w.y, h0[q * 4 + 1], acc0); acc1 = fmaf(w.y, h1[q * 4 + 1], acc1);
            acc0 = fmaf(w.z, h0[q * 4 + 2], acc0); acc1 = fmaf(w.z, h1[q * 4 + 2], acc1);
            acc0 = fmaf(w.w, h0[q * 4 + 3], acc0); acc1 = fmaf(w.w, h1[q * 4 + 3], acc1);
        }
        int n0 = half * 8 + n;
        gs[(n0 * 32 + ci) * 5 + gt]       = acc0;
        gs[((n0 + 1) * 32 + ci) * 5 + gt] = acc1;
    }
    __syncthreads();

    // ---- phase C: gates + output + m re-zero ----
    for (int t2 = threadIdx.x; t2 < 16 * 32; t2 += 256) {
        int nl = t2 >> 5, ii = t2 & 31;
        int v  = v0 + nl;
        const float* gp = gs + (size_t)t2 * 5;
        float rs = gp[0], zs = gp[1], in_ = gp[2], hn = gp[3];
        float hv = h[(size_t)v * H + ii];
        float r   = 1.f / (1.f + __expf(-rs));
        float z   = 1.f / (1.f + __expf(-zs));
        float nn2 = tanhf(in_ + r * hn);
        hout[(size_t)v * H + ii] = (1.f - z) * nn2 + z * hv;
        m[(size_t)v * H + ii]    = 0.f;        // pre-zero for next step
    }
}

// ---------------------------------------------------------------------------
extern "C" void kernel_launch(void* const* d_in, const int* in_sizes, int n_in,
                              void* d_out, int out_size, void* d_ws, size_t ws_size,
                              hipStream_t stream) {
    const float* node_feat = (const float*)d_in[0];
    const int*   edge_idx  = (const int*)  d_in[1];
    const float* edge_feat = (const float*)d_in[2];
    const float* W_np      = (const float*)d_in[3];
    const float* b_np      = (const float*)d_in[4];
    const float* W_e       = (const float*)d_in[5];
    const float* b_e       = (const float*)d_in[6];
    const float* W_ih      = (const float*)d_in[7];
    const float* W_hh      = (const float*)d_in[8];
    const float* b_ih      = (const float*)d_in[9];
    const float* b_hh      = (const float*)d_in[10];

    float* h      = (float*)d_ws;                             // N*H
    float* m      = h + (size_t)N_NODES * H;                  // N*H
    float* ef2    = m + (size_t)N_NODES * H;                  // E*EDGE_DIM
    int* rowptr   = (int*)(ef2 + (size_t)N_EDGES * EDGE_DIM); // N+1
    int* cursor   = rowptr + (N_NODES + 1);                   // N
    int* bsum     = cursor + N_NODES;                         // 80
    int* eperm    = bsum + 80;                                // E
    int* dst2     = eperm + N_EDGES;                          // E
    float* out    = (float*)d_out;

    // ---- one-time: zero m, build src-sorted CSR, permute ef ----
    hipMemsetAsync(m, 0, (size_t)N_NODES * H * sizeof(float), stream);
    hipMemsetAsync(cursor, 0, N_NODES * sizeof(int), stream);
    hist_src_kernel<<<(N_EDGES + 255) / 256, 256, 0, stream>>>(edge_idx, cursor);
    scan_a_kernel<<<(N_NODES + 255) / 256, 256, 0, stream>>>(cursor, rowptr, bsum);
    scan_b_kernel<<<1, 256, 0, stream>>>(rowptr, bsum, cursor);
    fill_src_kernel<<<(N_EDGES + 255) / 256, 256, 0, stream>>>(edge_idx, cursor,
                                                               eperm, dst2);
    permute_ef_kernel<<<(N_EDGES * EDGE_DIM + 255) / 256, 256, 0, stream>>>(
        edge_feat, eperm, ef2);

    // ---- h0 ----
    node_proj_kernel<<<(N_NODES * H + 255) / 256, 256, 0, stream>>>(
        node_feat, W_np, b_np, h);

    // ---- 3 propagation steps (2 dispatches each) ----
    for (int step = 0; step < STEPS; ++step) {
        fused_msg_kernel<<<N_NODES / 16, 576, 0, stream>>>(
            W_e, b_e, h, rowptr, dst2, ef2, m);
        float* dst_h = (step == STEPS - 1) ? out : h;
        gru_kernel<<<N_NODES / 16, 256, 0, stream>>>(W_ih, W_hh, b_ih, b_hh,
                                                     m, h, dst_h);
    }
}

// Round 6
// 313.078 us; speedup vs baseline: 1.0564x; 1.0564x over previous
//
#include <hip/hip_runtime.h>
#include <math.h>

#define N_NODES 20000
#define N_EDGES 160000
#define NODE_DIM 64
#define EDGE_DIM 16
#define H 32
#define STEPS 3

// ---------------------------------------------------------------------------
// CSR-by-src build (once per call): hist -> 2-level scan -> atomic fill that
// emits src-sorted src2/dst2/eperm; ef permuted into ef2.
// ---------------------------------------------------------------------------
__global__ void hist_src_kernel(const int* __restrict__ ei, int* __restrict__ deg) {
    int e = blockIdx.x * 256 + threadIdx.x;
    if (e < N_EDGES) atomicAdd(&deg[ei[e]], 1);               // row 0 = src
}

__global__ void scan_a_kernel(const int* __restrict__ deg,
                              int* __restrict__ part, int* __restrict__ bsum) {
    __shared__ int s[256];
    int v = blockIdx.x * 256 + threadIdx.x;
    int x = (v < N_NODES) ? deg[v] : 0;
    s[threadIdx.x] = x;
    __syncthreads();
    for (int off = 1; off < 256; off <<= 1) {
        int t = (threadIdx.x >= off) ? s[threadIdx.x - off] : 0;
        __syncthreads();
        s[threadIdx.x] += t;
        __syncthreads();
    }
    if (v < N_NODES) part[v] = s[threadIdx.x] - x;
    if (threadIdx.x == 255) bsum[blockIdx.x] = s[255];
}

__global__ void scan_b_kernel(int* __restrict__ rowptr,
                              const int* __restrict__ bsum,
                              int* __restrict__ cursor) {
    __shared__ int boff[80];
    if (threadIdx.x == 0) {
        int run = 0;
        for (int b = 0; b < 79; ++b) { boff[b] = run; run += bsum[b]; }
    }
    __syncthreads();
    for (int v = threadIdx.x; v < N_NODES; v += 256) {
        int r = rowptr[v] + boff[v >> 8];
        rowptr[v] = r;
        cursor[v] = r;
    }
    if (threadIdx.x == 0) rowptr[N_NODES] = N_EDGES;
}

__global__ void fill_src_kernel(const int* __restrict__ ei, int* __restrict__ cursor,
                                int* __restrict__ eperm, int* __restrict__ src2,
                                int* __restrict__ dst2) {
    int e = blockIdx.x * 256 + threadIdx.x;
    if (e < N_EDGES) {
        int s = ei[e];
        int slot = atomicAdd(&cursor[s], 1);
        eperm[slot] = e;
        src2[slot]  = s;
        dst2[slot]  = ei[N_EDGES + e];
    }
}

__global__ void permute_ef_kernel(const float* __restrict__ ef,
                                  const int* __restrict__ eperm,
                                  float* __restrict__ ef2) {
    int t = blockIdx.x * 256 + threadIdx.x;
    if (t < N_EDGES * EDGE_DIM) {
        int j = t >> 4;
        int d = t & 15;
        ef2[t] = ef[eperm[j] * EDGE_DIM + d];
    }
}

// ---------------------------------------------------------------------------
// node projection: h = node_feat @ W_np.T + b_np
// ---------------------------------------------------------------------------
__global__ void node_proj_kernel(const float* __restrict__ nf,
                                 const float* __restrict__ W,
                                 const float* __restrict__ b,
                                 float* __restrict__ h) {
    int tid = blockIdx.x * blockDim.x + threadIdx.x;
    if (tid >= N_NODES * H) return;
    int v = tid >> 5;
    int i = tid & 31;
    const float* __restrict__ row = nf + v * NODE_DIM;
    const float* __restrict__ w   = W + i * NODE_DIM;
    float acc = b[i];
#pragma unroll
    for (int d = 0; d < NODE_DIM; ++d) acc = fmaf(row[d], w[d], acc);
    h[tid] = acc;
}

// ---------------------------------------------------------------------------
// FUSED U-precompute + edge message (U lives only in LDS, never HBM).
// Phase 1 (= R4, proven): thread t owns column c=t; h rows staged in 2KB LDS,
//   read as same-address broadcast float4 (conflict-free). Swizzled U layout:
//   col c = i*16+4q+e -> Ul[n*576 + q*136 + i*4 + e]; bias i -> 544+i.
//   Edge-phase read up[q*34+lane] is lane-stride-16B = ideal (0 conflicts, R4).
// Phase 2 (NEW): half-wave hw takes a CONTIGUOUS chunk of the block's edge
//   range (equal edge counts -> balanced; src-sorted -> few src changes).
//   Lane i keeps U[s, i*16+..] in 4 float4 regs + bias, reloaded ONLY on src
//   change (~amortized 5x). Per edge: 4 same-address-broadcast float4 loads
//   of ef row (L1), 16 FMAs, 1 atomicAdd. No shfl, ~zero LDS per edge.
// ---------------------------------------------------------------------------
__global__ __launch_bounds__(576)
void fused_msg_kernel(const float* __restrict__ We,
                      const float* __restrict__ be,
                      const float* __restrict__ h,
                      const int* __restrict__ rowptr,
                      const int* __restrict__ src2,
                      const int* __restrict__ dst2,
                      const float* __restrict__ ef2,
                      float* __restrict__ m) {
    __shared__ float hs[16 * 32];     // 2 KB
    __shared__ float Ul[16 * 576];    // 36 KB (swizzled, 576-float row stride)

    int t = threadIdx.x;

    // ---- per-thread weight column (registers) ----
    float wreg[32];
    int p = -1;
    if (t < 512) {
        int L = t >> 4, q = (t >> 2) & 3, e = t & 3;
        int d = t & 15;
#pragma unroll
        for (int k = 0; k < H; ++k) wreg[k] = We[(L * H + k) * EDGE_DIM + d];
        p = q * 136 + L * 4 + e;
    } else if (t < 544) {
        int i = t - 512;
#pragma unroll
        for (int k = 0; k < H; ++k) wreg[k] = be[i * H + k];
        p = 544 + i;
    }

    int v0 = blockIdx.x * 16;

    // ---- stage h rows ----
    if (t < 512) hs[t] = h[(size_t)v0 * H + t];
    __syncthreads();

    // ---- phase 1: U into LDS (2 nodes per pass, broadcast f4 reads) ----
    if (p >= 0) {
        for (int n = 0; n < 16; n += 2) {
            const float4* __restrict__ hp0 = (const float4*)(hs + n * H);
            const float4* __restrict__ hp1 = (const float4*)(hs + (n + 1) * H);
            float a0 = 0.f, a1 = 0.f;
#pragma unroll
            for (int kk = 0; kk < 8; ++kk) {
                float4 q0 = hp0[kk];
                float4 q1 = hp1[kk];
                a0 = fmaf(wreg[4 * kk + 0], q0.x, a0);
                a1 = fmaf(wreg[4 * kk + 0], q1.x, a1);
                a0 = fmaf(wreg[4 * kk + 1], q0.y, a0);
                a1 = fmaf(wreg[4 * kk + 1], q1.y, a1);
                a0 = fmaf(wreg[4 * kk + 2], q0.z, a0);
                a1 = fmaf(wreg[4 * kk + 2], q1.z, a1);
                a0 = fmaf(wreg[4 * kk + 3], q0.w, a0);
                a1 = fmaf(wreg[4 * kk + 3], q1.w, a1);
            }
            Ul[n * 576 + p]       = a0;
            Ul[(n + 1) * 576 + p] = a1;
        }
    }
    __syncthreads();

    // ---- phase 2: contiguous edge chunks, register-cached U, direct ef ----
    int hw    = t >> 5;          // 0..17
    int lane  = t & 31;          // output component i
    int jbeg  = rowptr[v0];
    int jend  = rowptr[v0 + 16];
    int nE    = jend - jbeg;
    int chunk = (nE + 17) / 18;
    int ja    = jbeg + hw * chunk;
    int jz    = ja + chunk; if (jz > jend) jz = jend;

    int s_prev = -1;
    float4 u0 = {0,0,0,0}, u1 = {0,0,0,0}, u2 = {0,0,0,0}, u3 = {0,0,0,0};
    float  bv = 0.f;

    for (int j = ja; j < jz; ++j) {
        int s = src2[j];
        if (s != s_prev) {
            s_prev = s;
            int ls = s - v0;
            const float4* __restrict__ up = (const float4*)(Ul + ls * 576);
            u0 = up[0 * 34 + lane];   // cols lane*16 + 0..3
            u1 = up[1 * 34 + lane];   // cols lane*16 + 4..7
            u2 = up[2 * 34 + lane];   // cols lane*16 + 8..11
            u3 = up[3 * 34 + lane];   // cols lane*16 + 12..15
            bv = Ul[ls * 576 + 544 + lane];
        }
        const float4* __restrict__ ep = (const float4*)(ef2 + (size_t)j * EDGE_DIM);
        float4 e0 = ep[0];
        float4 e1 = ep[1];
        float4 e2 = ep[2];
        float4 e3 = ep[3];
        int dd = dst2[j];

        float msg = bv;
        msg = fmaf(e0.x, u0.x, msg);
        msg = fmaf(e0.y, u0.y, msg);
        msg = fmaf(e0.z, u0.z, msg);
        msg = fmaf(e0.w, u0.w, msg);
        msg = fmaf(e1.x, u1.x, msg);
        msg = fmaf(e1.y, u1.y, msg);
        msg = fmaf(e1.z, u1.z, msg);
        msg = fmaf(e1.w, u1.w, msg);
        msg = fmaf(e2.x, u2.x, msg);
        msg = fmaf(e2.y, u2.y, msg);
        msg = fmaf(e2.z, u2.z, msg);
        msg = fmaf(e2.w, u2.w, msg);
        msg = fmaf(e3.x, u3.x, msg);
        msg = fmaf(e3.y, u3.y, msg);
        msg = fmaf(e3.z, u3.z, msg);
        msg = fmaf(e3.w, u3.w, msg);

        atomicAdd(&m[(size_t)dd * H + lane], msg);
    }
}

// ---------------------------------------------------------------------------
// GRU v3 (= R4, proven): register-weight column-GEMM, xs LDS staging,
// self-zero of m for the next step's atomics.
// ---------------------------------------------------------------------------
__global__ __launch_bounds__(256, 4)
void gru_kernel(const float* __restrict__ Wih,
                const float* __restrict__ Whh,
                const float* __restrict__ bih,
                const float* __restrict__ bhh,
                float* __restrict__ m,
                const float* __restrict__ h,
                float* __restrict__ hout) {
    __shared__ float xs[16 * 64];        // [node][ m(32) | h(32) ]   4 KB
    __shared__ float gs[16 * 32 * 5];    // [node][i][gate + pad]    10 KB

    int c = threadIdx.x & 127;
    float4 wc[16];
    if (c < 96) {
        const float4* p = (const float4*)(Wih + c * H);
#pragma unroll
        for (int q = 0; q < 8; ++q) wc[q] = p[q];
    } else {
#pragma unroll
        for (int q = 0; q < 8; ++q) wc[q] = make_float4(0.f, 0.f, 0.f, 0.f);
    }
    int hrow = (c < 64) ? c : ((c >= 96) ? (c - 32) : -1);
    if (hrow >= 0) {
        const float4* p = (const float4*)(Whh + hrow * H);
#pragma unroll
        for (int q = 0; q < 8; ++q) wc[8 + q] = p[q];
    } else {
#pragma unroll
        for (int q = 0; q < 8; ++q) wc[8 + q] = make_float4(0.f, 0.f, 0.f, 0.f);
    }
    float bias;
    if (c < 64)      bias = bih[c] + bhh[c];      // r_sum / z_sum
    else if (c < 96) bias = bih[c];               // in
    else             bias = bhh[c - 32];          // hn

    int g    = threadIdx.x >> 5;    // node group 0..7
    int lane = threadIdx.x & 31;
    int half = threadIdx.x >> 7;    // 0: nodes 0..7, 1: nodes 8..15
    int ci   = c & 31;
    int gt   = c >> 5;

    int v0 = blockIdx.x * 16;
    {
        // ---- phase A: read m (and zero it), stage h ----
#pragma unroll
        for (int nn = 0; nn < 2; ++nn) {
            int n = g + nn * 8;
            int v = v0 + n;
            float mv = m[(size_t)v * H + lane];
            m[(size_t)v * H + lane] = 0.f;       // pre-zero for next step
            xs[n * 64 + lane]      = mv;
            xs[n * 64 + 32 + lane] = h[(size_t)v * H + lane];
        }
        __syncthreads();

        // ---- phase B: column-GEMM, 2 nodes per pass for ILP ----
#pragma unroll
        for (int n = 0; n < 8; n += 2) {
            const float4* x0 = (const float4*)(xs + (half * 8 + n) * 64);
            const float4* x1 = (const float4*)(xs + (half * 8 + n + 1) * 64);
            float acc0 = bias, acc1 = bias;
#pragma unroll
            for (int q = 0; q < 16; ++q) {
                float4 w = wc[q];
                float4 a = x0[q];
                float4 b = x1[q];
                acc0 = fmaf(w.x, a.x, acc0); acc1 = fmaf(w.x, b.x, acc1);
                acc0 = fmaf(w.y, a.y, acc0); acc1 = fmaf(w.y, b.y, acc1);
                acc0 = fmaf(w.z, a.z, acc0); acc1 = fmaf(w.z, b.z, acc1);
                acc0 = fmaf(w.w, a.w, acc0); acc1 = fmaf(w.w, b.w, acc1);
            }
            gs[((half * 8 + n)     * 32 + ci) * 5 + gt] = acc0;
            gs[((half * 8 + n + 1) * 32 + ci) * 5 + gt] = acc1;
        }
        __syncthreads();

        // ---- phase C: gates + output ----
        for (int t = threadIdx.x; t < 16 * 32; t += 256) {
            int nl = t >> 5, ii = t & 31;
            const float* gp = gs + (size_t)t * 5;
            float rs = gp[0], zs = gp[1], in_ = gp[2], hn = gp[3];
            float hv = xs[nl * 64 + 32 + ii];
            float r   = 1.f / (1.f + __expf(-rs));
            float z   = 1.f / (1.f + __expf(-zs));
            float nn2 = tanhf(in_ + r * hn);
            hout[(size_t)(v0 + nl) * H + ii] = (1.f - z) * nn2 + z * hv;
        }
    }
}

// ---------------------------------------------------------------------------
extern "C" void kernel_launch(void* const* d_in, const int* in_sizes, int n_in,
                              void* d_out, int out_size, void* d_ws, size_t ws_size,
                              hipStream_t stream) {
    const float* node_feat = (const float*)d_in[0];
    const int*   edge_idx  = (const int*)  d_in[1];
    const float* edge_feat = (const float*)d_in[2];
    const float* W_np      = (const float*)d_in[3];
    const float* b_np      = (const float*)d_in[4];
    const float* W_e       = (const float*)d_in[5];
    const float* b_e       = (const float*)d_in[6];
    const float* W_ih      = (const float*)d_in[7];
    const float* W_hh      = (const float*)d_in[8];
    const float* b_ih      = (const float*)d_in[9];
    const float* b_hh      = (const float*)d_in[10];

    float* h      = (float*)d_ws;                             // N*H
    float* m      = h + (size_t)N_NODES * H;                  // N*H
    float* ef2    = m + (size_t)N_NODES * H;                  // E*EDGE_DIM
    int* rowptr   = (int*)(ef2 + (size_t)N_EDGES * EDGE_DIM); // N+1
    int* cursor   = rowptr + (N_NODES + 1);                   // N
    int* bsum     = cursor + N_NODES;                         // 80
    int* eperm    = bsum + 80;                                // E
    int* src2     = eperm + N_EDGES;                          // E
    int* dst2     = src2 + N_EDGES;                           // E
    float* out    = (float*)d_out;

    // ---- one-time: zero m, build src-sorted CSR, permute ef ----
    hipMemsetAsync(m, 0, (size_t)N_NODES * H * sizeof(float), stream);
    hipMemsetAsync(cursor, 0, N_NODES * sizeof(int), stream);
    hist_src_kernel<<<(N_EDGES + 255) / 256, 256, 0, stream>>>(edge_idx, cursor);
    scan_a_kernel<<<(N_NODES + 255) / 256, 256, 0, stream>>>(cursor, rowptr, bsum);
    scan_b_kernel<<<1, 256, 0, stream>>>(rowptr, bsum, cursor);
    fill_src_kernel<<<(N_EDGES + 255) / 256, 256, 0, stream>>>(edge_idx, cursor,
                                                               eperm, src2, dst2);
    permute_ef_kernel<<<(N_EDGES * EDGE_DIM + 255) / 256, 256, 0, stream>>>(
        edge_feat, eperm, ef2);

    // ---- h0 ----
    node_proj_kernel<<<(N_NODES * H + 255) / 256, 256, 0, stream>>>(
        node_feat, W_np, b_np, h);

    // ---- 3 propagation steps (2 dispatches each) ----
    for (int step = 0; step < STEPS; ++step) {
        fused_msg_kernel<<<N_NODES / 16, 576, 0, stream>>>(
            W_e, b_e, h, rowptr, src2, dst2, ef2, m);
        float* dst_h = (step == STEPS - 1) ? out : h;
        gru_kernel<<<N_NODES / 16, 256, 0, stream>>>(W_ih, W_hh, b_ih, b_hh,
                                                     m, h, dst_h);
    }
}

// Round 7
// 302.787 us; speedup vs baseline: 1.0923x; 1.0340x over previous
//
#include <hip/hip_runtime.h>
#include <math.h>

#define N_NODES 20000
#define N_EDGES 160000
#define NODE_DIM 64
#define EDGE_DIM 16
#define H 32
#define STEPS 3

// ---------------------------------------------------------------------------
// CSR-by-src build (once per call): hist -> 2-level scan -> atomic fill that
// emits src-sorted sd2 (packed src,dst) + eperm; ef permuted into ef2.
// ---------------------------------------------------------------------------
__global__ void hist_src_kernel(const int* __restrict__ ei, int* __restrict__ deg) {
    int e = blockIdx.x * 256 + threadIdx.x;
    if (e < N_EDGES) atomicAdd(&deg[ei[e]], 1);               // row 0 = src
}

__global__ void scan_a_kernel(const int* __restrict__ deg,
                              int* __restrict__ part, int* __restrict__ bsum) {
    __shared__ int s[256];
    int v = blockIdx.x * 256 + threadIdx.x;
    int x = (v < N_NODES) ? deg[v] : 0;
    s[threadIdx.x] = x;
    __syncthreads();
    for (int off = 1; off < 256; off <<= 1) {
        int t = (threadIdx.x >= off) ? s[threadIdx.x - off] : 0;
        __syncthreads();
        s[threadIdx.x] += t;
        __syncthreads();
    }
    if (v < N_NODES) part[v] = s[threadIdx.x] - x;
    if (threadIdx.x == 255) bsum[blockIdx.x] = s[255];
}

__global__ void scan_b_kernel(int* __restrict__ rowptr,
                              const int* __restrict__ bsum,
                              int* __restrict__ cursor) {
    __shared__ int boff[80];
    if (threadIdx.x == 0) {
        int run = 0;
        for (int b = 0; b < 79; ++b) { boff[b] = run; run += bsum[b]; }
    }
    __syncthreads();
    for (int v = threadIdx.x; v < N_NODES; v += 256) {
        int r = rowptr[v] + boff[v >> 8];
        rowptr[v] = r;
        cursor[v] = r;
    }
    if (threadIdx.x == 0) rowptr[N_NODES] = N_EDGES;
}

__global__ void fill_src_kernel(const int* __restrict__ ei, int* __restrict__ cursor,
                                int* __restrict__ eperm, int2* __restrict__ sd2) {
    int e = blockIdx.x * 256 + threadIdx.x;
    if (e < N_EDGES) {
        int s = ei[e];
        int slot = atomicAdd(&cursor[s], 1);
        eperm[slot] = e;
        sd2[slot]   = make_int2(s, ei[N_EDGES + e]);
    }
}

__global__ void permute_ef_kernel(const float* __restrict__ ef,
                                  const int* __restrict__ eperm,
                                  float* __restrict__ ef2) {
    int t = blockIdx.x * 256 + threadIdx.x;
    if (t < N_EDGES * EDGE_DIM) {
        int j = t >> 4;
        int d = t & 15;
        ef2[t] = ef[eperm[j] * EDGE_DIM + d];
    }
}

// ---------------------------------------------------------------------------
// node projection: h = node_feat @ W_np.T + b_np
// ---------------------------------------------------------------------------
__global__ void node_proj_kernel(const float* __restrict__ nf,
                                 const float* __restrict__ W,
                                 const float* __restrict__ b,
                                 float* __restrict__ h) {
    int tid = blockIdx.x * blockDim.x + threadIdx.x;
    if (tid >= N_NODES * H) return;
    int v = tid >> 5;
    int i = tid & 31;
    const float* __restrict__ row = nf + v * NODE_DIM;
    const float* __restrict__ w   = W + i * NODE_DIM;
    float acc = b[i];
#pragma unroll
    for (int d = 0; d < NODE_DIM; ++d) acc = fmaf(row[d], w[d], acc);
    h[tid] = acc;
}

// ---------------------------------------------------------------------------
// FUSED U-precompute + edge message (U lives only in LDS, never HBM).
// Phase 1 (proven): thread t owns column c=t; h rows staged in 2KB LDS,
//   read as same-address broadcast float4 (conflict-free). Swizzled U layout:
//   col c = i*16+4q+e -> Ul[n*576 + q*136 + i*4 + e]; bias i -> 544+i.
//   Edge-phase read up[q*34+lane] is lane-stride-16B (0 conflicts, verified).
// Phase 2 (NEW: 1-deep software pipeline): half-wave hw owns a contiguous
//   edge chunk. Per iteration, PREFETCH next edge's packed (src,dst) int2 +
//   4 float4 ef quads BEFORE the current edge's U-reload/FMA/atomic, hiding
//   VMEM latency under ~100 cyc of compute. U regs reloaded only on src
//   change (src-sorted => ~2 reloads per chunk). Clamped prefetch index
//   avoids divergence. Per edge: 1x int2 + 4x float4 loads, 16 FMA, 1 atomic.
// ---------------------------------------------------------------------------
__global__ __launch_bounds__(576)
void fused_msg_kernel(const float* __restrict__ We,
                      const float* __restrict__ be,
                      const float* __restrict__ h,
                      const int* __restrict__ rowptr,
                      const int2* __restrict__ sd2,
                      const float* __restrict__ ef2,
                      float* __restrict__ m) {
    __shared__ float hs[16 * 32];     // 2 KB
    __shared__ float Ul[16 * 576];    // 36 KB (swizzled, 576-float row stride)

    int t = threadIdx.x;

    // ---- per-thread weight column (registers) ----
    float wreg[32];
    int p = -1;
    if (t < 512) {
        int L = t >> 4, q = (t >> 2) & 3, e = t & 3;
        int d = t & 15;
#pragma unroll
        for (int k = 0; k < H; ++k) wreg[k] = We[(L * H + k) * EDGE_DIM + d];
        p = q * 136 + L * 4 + e;
    } else if (t < 544) {
        int i = t - 512;
#pragma unroll
        for (int k = 0; k < H; ++k) wreg[k] = be[i * H + k];
        p = 544 + i;
    }

    int v0 = blockIdx.x * 16;

    // ---- stage h rows ----
    if (t < 512) hs[t] = h[(size_t)v0 * H + t];
    __syncthreads();

    // ---- phase 1: U into LDS (2 nodes per pass, broadcast f4 reads) ----
    if (p >= 0) {
        for (int n = 0; n < 16; n += 2) {
            const float4* __restrict__ hp0 = (const float4*)(hs + n * H);
            const float4* __restrict__ hp1 = (const float4*)(hs + (n + 1) * H);
            float a0 = 0.f, a1 = 0.f;
#pragma unroll
            for (int kk = 0; kk < 8; ++kk) {
                float4 q0 = hp0[kk];
                float4 q1 = hp1[kk];
                a0 = fmaf(wreg[4 * kk + 0], q0.x, a0);
                a1 = fmaf(wreg[4 * kk + 0], q1.x, a1);
                a0 = fmaf(wreg[4 * kk + 1], q0.y, a0);
                a1 = fmaf(wreg[4 * kk + 1], q1.y, a1);
                a0 = fmaf(wreg[4 * kk + 2], q0.z, a0);
                a1 = fmaf(wreg[4 * kk + 2], q1.z, a1);
                a0 = fmaf(wreg[4 * kk + 3], q0.w, a0);
                a1 = fmaf(wreg[4 * kk + 3], q1.w, a1);
            }
            Ul[n * 576 + p]       = a0;
            Ul[(n + 1) * 576 + p] = a1;
        }
    }
    __syncthreads();

    // ---- phase 2: contiguous chunks, reg-cached U, 1-deep prefetch ----
    int hw    = t >> 5;          // 0..17
    int lane  = t & 31;          // output component i
    int jbeg  = rowptr[v0];
    int jend  = rowptr[v0 + 16];
    int nE    = jend - jbeg;
    int chunk = (nE + 17) / 18;
    int ja    = jbeg + hw * chunk;
    int jz    = ja + chunk; if (jz > jend) jz = jend;

    if (ja < jz) {
        int s_prev = -1;
        float4 u0 = {0,0,0,0}, u1 = {0,0,0,0}, u2 = {0,0,0,0}, u3 = {0,0,0,0};
        float  bv = 0.f;

        int2 sd = sd2[ja];
        const float4* __restrict__ ep0 = (const float4*)(ef2 + (size_t)ja * EDGE_DIM);
        float4 e0 = ep0[0], e1 = ep0[1], e2 = ep0[2], e3 = ep0[3];

        for (int j = ja; j < jz; ++j) {
            // prefetch next edge (clamped -> no divergence, no branch)
            int jn = (j + 1 < jz) ? (j + 1) : j;
            int2 sdn = sd2[jn];
            const float4* __restrict__ epn =
                (const float4*)(ef2 + (size_t)jn * EDGE_DIM);
            float4 f0 = epn[0], f1 = epn[1], f2 = epn[2], f3 = epn[3];

            // U regs reload only on src change
            if (sd.x != s_prev) {
                s_prev = sd.x;
                int ls = sd.x - v0;
                const float4* __restrict__ up = (const float4*)(Ul + ls * 576);
                u0 = up[0 * 34 + lane];
                u1 = up[1 * 34 + lane];
                u2 = up[2 * 34 + lane];
                u3 = up[3 * 34 + lane];
                bv = Ul[ls * 576 + 544 + lane];
            }

            float msg = bv;
            msg = fmaf(e0.x, u0.x, msg);
            msg = fmaf(e0.y, u0.y, msg);
            msg = fmaf(e0.z, u0.z, msg);
            msg = fmaf(e0.w, u0.w, msg);
            msg = fmaf(e1.x, u1.x, msg);
            msg = fmaf(e1.y, u1.y, msg);
            msg = fmaf(e1.z, u1.z, msg);
            msg = fmaf(e1.w, u1.w, msg);
            msg = fmaf(e2.x, u2.x, msg);
            msg = fmaf(e2.y, u2.y, msg);
            msg = fmaf(e2.z, u2.z, msg);
            msg = fmaf(e2.w, u2.w, msg);
            msg = fmaf(e3.x, u3.x, msg);
            msg = fmaf(e3.y, u3.y, msg);
            msg = fmaf(e3.z, u3.z, msg);
            msg = fmaf(e3.w, u3.w, msg);

            atomicAdd(&m[(size_t)sd.y * H + lane], msg);

            sd = sdn;
            e0 = f0; e1 = f1; e2 = f2; e3 = f3;
        }
    }
}

// ---------------------------------------------------------------------------
// GRU (proven R4/R6): register-weight column-GEMM, xs LDS staging,
// self-zero of m for the next step's atomics.
// ---------------------------------------------------------------------------
__global__ __launch_bounds__(256, 4)
void gru_kernel(const float* __restrict__ Wih,
                const float* __restrict__ Whh,
                const float* __restrict__ bih,
                const float* __restrict__ bhh,
                float* __restrict__ m,
                const float* __restrict__ h,
                float* __restrict__ hout) {
    __shared__ float xs[16 * 64];        // [node][ m(32) | h(32) ]   4 KB
    __shared__ float gs[16 * 32 * 5];    // [node][i][gate + pad]    10 KB

    int c = threadIdx.x & 127;
    float4 wc[16];
    if (c < 96) {
        const float4* p = (const float4*)(Wih + c * H);
#pragma unroll
        for (int q = 0; q < 8; ++q) wc[q] = p[q];
    } else {
#pragma unroll
        for (int q = 0; q < 8; ++q) wc[q] = make_float4(0.f, 0.f, 0.f, 0.f);
    }
    int hrow = (c < 64) ? c : ((c >= 96) ? (c - 32) : -1);
    if (hrow >= 0) {
        const float4* p = (const float4*)(Whh + hrow * H);
#pragma unroll
        for (int q = 0; q < 8; ++q) wc[8 + q] = p[q];
    } else {
#pragma unroll
        for (int q = 0; q < 8; ++q) wc[8 + q] = make_float4(0.f, 0.f, 0.f, 0.f);
    }
    float bias;
    if (c < 64)      bias = bih[c] + bhh[c];      // r_sum / z_sum
    else if (c < 96) bias = bih[c];               // in
    else             bias = bhh[c - 32];          // hn

    int g    = threadIdx.x >> 5;    // node group 0..7
    int lane = threadIdx.x & 31;
    int half = threadIdx.x >> 7;    // 0: nodes 0..7, 1: nodes 8..15
    int ci   = c & 31;
    int gt   = c >> 5;

    int v0 = blockIdx.x * 16;
    {
        // ---- phase A: read m (and zero it), stage h ----
#pragma unroll
        for (int nn = 0; nn < 2; ++nn) {
            int n = g + nn * 8;
            int v = v0 + n;
            float mv = m[(size_t)v * H + lane];
            m[(size_t)v * H + lane] = 0.f;       // pre-zero for next step
            xs[n * 64 + lane]      = mv;
            xs[n * 64 + 32 + lane] = h[(size_t)v * H + lane];
        }
        __syncthreads();

        // ---- phase B: column-GEMM, 2 nodes per pass for ILP ----
#pragma unroll
        for (int n = 0; n < 8; n += 2) {
            const float4* x0 = (const float4*)(xs + (half * 8 + n) * 64);
            const float4* x1 = (const float4*)(xs + (half * 8 + n + 1) * 64);
            float acc0 = bias, acc1 = bias;
#pragma unroll
            for (int q = 0; q < 16; ++q) {
                float4 w = wc[q];
                float4 a = x0[q];
                float4 b = x1[q];
                acc0 = fmaf(w.x, a.x, acc0); acc1 = fmaf(w.x, b.x, acc1);
                acc0 = fmaf(w.y, a.y, acc0); acc1 = fmaf(w.y, b.y, acc1);
                acc0 = fmaf(w.z, a.z, acc0); acc1 = fmaf(w.z, b.z, acc1);
                acc0 = fmaf(w.w, a.w, acc0); acc1 = fmaf(w.w, b.w, acc1);
            }
            gs[((half * 8 + n)     * 32 + ci) * 5 + gt] = acc0;
            gs[((half * 8 + n + 1) * 32 + ci) * 5 + gt] = acc1;
        }
        __syncthreads();

        // ---- phase C: gates + output ----
        for (int t = threadIdx.x; t < 16 * 32; t += 256) {
            int nl = t >> 5, ii = t & 31;
            const float* gp = gs + (size_t)t * 5;
            float rs = gp[0], zs = gp[1], in_ = gp[2], hn = gp[3];
            float hv = xs[nl * 64 + 32 + ii];
            float r   = 1.f / (1.f + __expf(-rs));
            float z   = 1.f / (1.f + __expf(-zs));
            float nn2 = tanhf(in_ + r * hn);
            hout[(size_t)(v0 + nl) * H + ii] = (1.f - z) * nn2 + z * hv;
        }
    }
}

// ---------------------------------------------------------------------------
extern "C" void kernel_launch(void* const* d_in, const int* in_sizes, int n_in,
                              void* d_out, int out_size, void* d_ws, size_t ws_size,
                              hipStream_t stream) {
    const float* node_feat = (const float*)d_in[0];
    const int*   edge_idx  = (const int*)  d_in[1];
    const float* edge_feat = (const float*)d_in[2];
    const float* W_np      = (const float*)d_in[3];
    const float* b_np      = (const float*)d_in[4];
    const float* W_e       = (const float*)d_in[5];
    const float* b_e       = (const float*)d_in[6];
    const float* W_ih      = (const float*)d_in[7];
    const float* W_hh      = (const float*)d_in[8];
    const float* b_ih      = (const float*)d_in[9];
    const float* b_hh      = (const float*)d_in[10];

    float* h      = (float*)d_ws;                             // N*H
    float* m      = h + (size_t)N_NODES * H;                  // N*H
    float* ef2    = m + (size_t)N_NODES * H;                  // E*EDGE_DIM
    int* rowptr   = (int*)(ef2 + (size_t)N_EDGES * EDGE_DIM); // N+1
    int* cursor   = rowptr + (N_NODES + 1);                   // N
    int* bsum     = cursor + N_NODES;                         // 80
    int* eperm    = bsum + 80;                                // E
    int2* sd2     = (int2*)(eperm + N_EDGES);                 // E int2 (8B aligned)
    float* out    = (float*)d_out;

    // ---- one-time: zero m, build src-sorted CSR, permute ef ----
    hipMemsetAsync(m, 0, (size_t)N_NODES * H * sizeof(float), stream);
    hipMemsetAsync(cursor, 0, N_NODES * sizeof(int), stream);
    hist_src_kernel<<<(N_EDGES + 255) / 256, 256, 0, stream>>>(edge_idx, cursor);
    scan_a_kernel<<<(N_NODES + 255) / 256, 256, 0, stream>>>(cursor, rowptr, bsum);
    scan_b_kernel<<<1, 256, 0, stream>>>(rowptr, bsum, cursor);
    fill_src_kernel<<<(N_EDGES + 255) / 256, 256, 0, stream>>>(edge_idx, cursor,
                                                               eperm, sd2);
    permute_ef_kernel<<<(N_EDGES * EDGE_DIM + 255) / 256, 256, 0, stream>>>(
        edge_feat, eperm, ef2);

    // ---- h0 ----
    node_proj_kernel<<<(N_NODES * H + 255) / 256, 256, 0, stream>>>(
        node_feat, W_np, b_np, h);

    // ---- 3 propagation steps (2 dispatches each) ----
    for (int step = 0; step < STEPS; ++step) {
        fused_msg_kernel<<<N_NODES / 16, 576, 0, stream>>>(
            W_e, b_e, h, rowptr, sd2, ef2, m);
        float* dst_h = (step == STEPS - 1) ? out : h;
        gru_kernel<<<N_NODES / 16, 256, 0, stream>>>(W_ih, W_hh, b_ih, b_hh,
                                                     m, h, dst_h);
    }
}